// Round 7
// baseline (613.129 us; speedup 1.0000x reference)
//
#include <hip/hip_runtime.h>

#define BATCH 256
#define TSTEPS 2048
#define INSZ 64
#define HID 128
#define OUTSZ 64
#define NTHR 512

typedef float v2f __attribute__((ext_vector_type(2)));
typedef float v4f __attribute__((ext_vector_type(4)));

// DPP cross-lane move (VALU pipe). Patterns stay within a 16-lane row.
template <int CTRL>
__device__ __forceinline__ float dppf(float v) {
  return __int_as_float(__builtin_amdgcn_update_dpp(
      0, __float_as_int(v), CTRL, 0xF, 0xF, true));
}
#define DPP_XOR1 0xB1    // quad_perm:[1,0,3,2]
#define DPP_XOR2 0x4E    // quad_perm:[2,3,0,1]
#define DPP_XOR15 0x140  // row_mirror (lane ^ 15 within 16)
#define DPP_XOR8 0x128   // row_ror:8  (lane ^ 8  within 16)

// guaranteed packed f32 math (2 MACs / instr)
__device__ __forceinline__ v2f pk_mul(v2f a, v2f b) {
  v2f d; asm("v_pk_mul_f32 %0, %1, %2" : "=v"(d) : "v"(a), "v"(b)); return d;
}
__device__ __forceinline__ v2f pk_fma(v2f a, v2f b, v2f c) {
  v2f d; asm("v_pk_fma_f32 %0, %1, %2, %3" : "=v"(d) : "v"(a), "v"(b), "v"(c)); return d;
}

// 512 threads / 8 waves per batch element (2 waves per SIMD).
//   k-group s = tid&15 : h-k range [8s,8s+8), x-k range [4s,4s+4)
//   j-group g = tid>>4 : j range [4g, 4g+4)   (32 j-groups)
// Slot m holds row j = 4g + (m ^ c),  c = (s0^s2)|((s1^s2)<<1); DPP butterfly
// reduce (xor1 slots, xor2 slots, xor15, xor8 lanes); lanes s<4 write h.
// h padded: addr = k + (k>>3)*4. x NEVER touches LDS: per-thread 16B
// global_load_dwordx4 via opaque inline asm, 4-deep pipeline, counted
// s_waitcnt vmcnt(3) folded into the step-top barrier (never drains).
__launch_bounds__(NTHR, 1)
__global__ void rnn_gx_kernel(const float* __restrict__ x,
                              const float* __restrict__ Wx_w,
                              const float* __restrict__ Wx_b,
                              const float* __restrict__ Wh_w,
                              const float* __restrict__ Wh_b,
                              const float* __restrict__ fc_w,
                              const float* __restrict__ fc_b,
                              float* __restrict__ out) {
  const int b = blockIdx.x;
  const int tid = threadIdx.x;
  const int s = tid & 15;  // k-group (= lane&15)
  const int g = tid >> 4;  // j-group (0..31)
  const int s0 = s & 1, s1 = (s >> 1) & 1, s2 = (s >> 2) & 1;
  const int c = (s0 ^ s2) | ((s1 ^ s2) << 1);
  const int jf = 4 * g + c;                  // the j this lane finalizes
  const int jp = jf + ((jf >> 3) << 2);      // padded write index

  __shared__ __align__(16) float hA[192], hB[192];  // padded h buffers

  // ---- weights: slot m holds row j = 4g + (m ^ c) ----
  v2f wh2[4][4], wx2[4][2];
#pragma unroll
  for (int m = 0; m < 4; ++m) {
    const int row = 4 * g + (m ^ c);
    const float* p = Wh_w + row * HID + 8 * s;
    v4f t0 = *(const v4f*)p;
    v4f t1 = *(const v4f*)(p + 4);
    wh2[m][0] = (v2f){t0.x, t0.y};
    wh2[m][1] = (v2f){t0.z, t0.w};
    wh2[m][2] = (v2f){t1.x, t1.y};
    wh2[m][3] = (v2f){t1.z, t1.w};
    const float* q = Wx_w + row * INSZ + 4 * s;
    v4f t2 = *(const v4f*)q;
    wx2[m][0] = (v2f){t2.x, t2.y};
    wx2[m][1] = (v2f){t2.z, t2.w};
  }
  const float bc = Wx_b[jf] + Wh_b[jf];

  const float* xg = x + (size_t)b * TSTEPS * INSZ;

  // ---- x pipeline: 4 register buffers, byte voffsets, clamped tail ----
  unsigned volim = (TSTEPS - 1) * 256u + 16u * s;
  unsigned voA = 16u * s;
  unsigned voB = voA + 256u;
  unsigned voC = voA + 512u;
  unsigned voD = voA + 768u;
  v4f xa, xb, xc_, xd;
  asm volatile("global_load_dwordx4 %0, %1, %2" : "=v"(xa) : "v"(voA), "s"(xg));
  asm volatile("global_load_dwordx4 %0, %1, %2" : "=v"(xb) : "v"(voB), "s"(xg));
  asm volatile("global_load_dwordx4 %0, %1, %2" : "=v"(xc_) : "v"(voC), "s"(xg));
  asm volatile("global_load_dwordx4 %0, %1, %2" : "=v"(xd) : "v"(voD), "s"(xg));

  // ---- init h0 = 0 ----
  if (tid < 192) hA[tid] = 0.f;

  auto step = [&](const float* hin, float* hout, v4f& xbuf, unsigned& vo) {
    // step-top barrier: prev ds_write drained (lgkm) + this step's x landed
    // (vmcnt(3): exactly 4 opaque loads in flight after each issue). The
    // "+v"(xbuf) ties the wait to the buffer so consumers can't float above.
    asm volatile("s_waitcnt vmcnt(3) lgkmcnt(0)\n\ts_barrier"
                 : "+v"(xbuf) :: "memory");

    // consume x, then immediately issue this buffer's replacement (t+4)
    v2f xx0 = (v2f){xbuf.x, xbuf.y}, xx1 = (v2f){xbuf.z, xbuf.w};
    vo += 1024u;
    vo = vo < volim ? vo : volim;
    asm volatile("global_load_dwordx4 %0, %1, %2" : "=v"(xbuf) : "v"(vo), "s"(xg));

    // h reads (the only LDS loads)
    const float* hp = hin + 12 * s;
    v4f h0 = *(const v4f*)hp;
    v4f h1 = *(const v4f*)(hp + 4);
    v2f hx0 = (v2f){h0.x, h0.y}, hx1 = (v2f){h0.z, h0.w};
    v2f hx2 = (v2f){h1.x, h1.y}, hx3 = (v2f){h1.z, h1.w};

    float a0, a1, a2, a3;
    float* aptr[4] = {&a0, &a1, &a2, &a3};
#pragma unroll
    for (int m = 0; m < 4; ++m) {
      v2f acc = pk_mul(wx2[m][0], xx0);  // x-part first (ready earliest)
      acc = pk_fma(wx2[m][1], xx1, acc);
      acc = pk_fma(wh2[m][0], hx0, acc);
      acc = pk_fma(wh2[m][1], hx1, acc);
      acc = pk_fma(wh2[m][2], hx2, acc);
      acc = pk_fma(wh2[m][3], hx3, acc);
      *aptr[m] = acc.x + acc.y;
    }

    // DPP butterfly reduce-scatter over the 16-lane k-group
    float b0 = a0 + dppf<DPP_XOR1>(a1);
    float b1 = a2 + dppf<DPP_XOR1>(a3);
    float w  = b0 + dppf<DPP_XOR2>(b1);
    float u  = w + dppf<DPP_XOR15>(w);
    float z  = u + dppf<DPP_XOR8>(u);

    // tanh(z+bc) = 1 - 2/(exp2(2*(z+bc)*log2e)+1)
    z += bc;
    float e = __builtin_amdgcn_exp2f(z * 2.8853900817779268f);
    float hn = fmaf(-2.f, __builtin_amdgcn_rcpf(e + 1.f), 1.f);

    if (s < 4) hout[jp] = hn;  // lanes s=0..3 hold j=4g+s
  };

  // ---- recurrence: rolled loop, 4 steps/iter (h parity + x buffers static) ----
  for (int t4 = 0; t4 < TSTEPS / 4; ++t4) {
    // re-pin weights to arch VGPRs every iteration (blocks AGPR shuttling)
#pragma unroll
    for (int m = 0; m < 4; ++m) {
      asm("" : "+v"(wh2[m][0]), "+v"(wh2[m][1]), "+v"(wh2[m][2]), "+v"(wh2[m][3]));
      asm("" : "+v"(wx2[m][0]), "+v"(wx2[m][1]));
    }
    step(hA, hB, xa, voA);
    step(hB, hA, xb, voB);
    step(hA, hB, xc_, voC);
    step(hB, hA, xd, voD);
  }

  // drain all in-flight x loads before their VGPRs can be reused; final sync
  asm volatile("s_waitcnt vmcnt(0) lgkmcnt(0)\n\ts_barrier" ::: "memory");

  // ---- epilogue: logits + softmax over 64, one wave; final h in hA ----
  if (tid < 64) {
    float acc = fc_b[tid];
    const float* fr = fc_w + tid * HID;
#pragma unroll
    for (int k8 = 0; k8 < 16; ++k8) {
      v4f w0 = *(const v4f*)(fr + 8 * k8);
      v4f w1 = *(const v4f*)(fr + 8 * k8 + 4);
      const float* hh = &hA[12 * k8];
      v4f p0 = *(const v4f*)hh;
      v4f p1 = *(const v4f*)(hh + 4);
      acc = fmaf(w0.x, p0.x, acc);
      acc = fmaf(w0.y, p0.y, acc);
      acc = fmaf(w0.z, p0.z, acc);
      acc = fmaf(w0.w, p0.w, acc);
      acc = fmaf(w1.x, p1.x, acc);
      acc = fmaf(w1.y, p1.y, acc);
      acc = fmaf(w1.z, p1.z, acc);
      acc = fmaf(w1.w, p1.w, acc);
    }
    float m = acc;
#pragma unroll
    for (int off = 32; off >= 1; off >>= 1) m = fmaxf(m, __shfl_xor(m, off, 64));
    float e = __builtin_amdgcn_exp2f((acc - m) * 1.4426950408889634f);
    float ssum = e;
#pragma unroll
    for (int off = 32; off >= 1; off >>= 1) ssum += __shfl_xor(ssum, off, 64);
    out[b * OUTSZ + tid] = e / ssum;
  }
}

extern "C" void kernel_launch(void* const* d_in, const int* in_sizes, int n_in,
                              void* d_out, int out_size, void* d_ws, size_t ws_size,
                              hipStream_t stream) {
  const float* x    = (const float*)d_in[0];
  const float* Wx_w = (const float*)d_in[1];
  const float* Wx_b = (const float*)d_in[2];
  const float* Wh_w = (const float*)d_in[3];
  const float* Wh_b = (const float*)d_in[4];
  const float* fc_w = (const float*)d_in[5];
  const float* fc_b = (const float*)d_in[6];
  float* out = (float*)d_out;

  rnn_gx_kernel<<<BATCH, NTHR, 0, stream>>>(x, Wx_w, Wx_b, Wh_w, Wh_b, fc_w, fc_b, out);
}

// Round 8
// 550.747 us; speedup vs baseline: 1.1133x; 1.1133x over previous
//
#include <hip/hip_runtime.h>

#define BATCH 256
#define TSTEPS 2048
#define INSZ 64
#define HID 128
#define OUTSZ 64
#define NTHR 512
#define CHUNK 32                 // timesteps of x per staging buffer (8KB)
#define NCHUNK (TSTEPS / CHUNK)  // 64

typedef float v2f __attribute__((ext_vector_type(2)));
typedef float v4f __attribute__((ext_vector_type(4)));

#define AS1 __attribute__((address_space(1)))
#define AS3 __attribute__((address_space(3)))

// DPP cross-lane move (VALU pipe). Patterns stay within a 16-lane row.
template <int CTRL>
__device__ __forceinline__ float dppf(float v) {
  return __int_as_float(__builtin_amdgcn_update_dpp(
      0, __float_as_int(v), CTRL, 0xF, 0xF, true));
}
#define DPP_XOR1 0xB1    // quad_perm:[1,0,3,2]
#define DPP_XOR2 0x4E    // quad_perm:[2,3,0,1]
#define DPP_XOR15 0x140  // row_mirror (lane ^ 15 within 16)
#define DPP_XOR8 0x128   // row_ror:8  (lane ^ 8  within 16)

// 512 threads / 8 waves per batch element (2 waves per SIMD).
//   k-group s = tid&15 : h-k range [8s,8s+8), x-k range [4s,4s+4)
//   j-group g = tid>>4 : j range [4g, 4g+4)   (32 j-groups)
// Slot m holds row j = 4g + (m ^ c),  c = (s0^s2)|((s1^s2)<<1); DPP butterfly
// reduce (xor1 slots, xor2 slots, xor15, xor8 lanes); lanes s<4 write h.
// h padded: addr = k + (k>>3)*4. x staged global->LDS in 32-step chunks.
// The 24-op MAC sequence is two monolithic asm blocks with weights as direct
// "v" operands -> forces arch-VGPR residency (no AGPR shuttling), minimal
// instruction count.
__launch_bounds__(NTHR, 1)
__global__ void rnn_masm_kernel(const float* __restrict__ x,
                                const float* __restrict__ Wx_w,
                                const float* __restrict__ Wx_b,
                                const float* __restrict__ Wh_w,
                                const float* __restrict__ Wh_b,
                                const float* __restrict__ fc_w,
                                const float* __restrict__ fc_b,
                                float* __restrict__ out) {
  const int b = blockIdx.x;
  const int tid = threadIdx.x;
  const int s = tid & 15;  // k-group (= lane&15)
  const int g = tid >> 4;  // j-group (0..31)
  const int s0 = s & 1, s1 = (s >> 1) & 1, s2 = (s >> 2) & 1;
  const int c = (s0 ^ s2) | ((s1 ^ s2) << 1);
  const int jf = 4 * g + c;                  // the j this lane finalizes
  const int jp = jf + ((jf >> 3) << 2);      // padded write index

  __shared__ __align__(16) float hA[192], hB[192];        // padded h buffers
  __shared__ __align__(16) float xsm[2][CHUNK * INSZ];    // 2 x 8KB

  // ---- weights: slot m holds row j = 4g + (m ^ c) ----
  v2f wh2[4][4], wx2[4][2];
#pragma unroll
  for (int m = 0; m < 4; ++m) {
    const int row = 4 * g + (m ^ c);
    const float* p = Wh_w + row * HID + 8 * s;
    v4f t0 = *(const v4f*)p;
    v4f t1 = *(const v4f*)(p + 4);
    wh2[m][0] = (v2f){t0.x, t0.y};
    wh2[m][1] = (v2f){t0.z, t0.w};
    wh2[m][2] = (v2f){t1.x, t1.y};
    wh2[m][3] = (v2f){t1.z, t1.w};
    const float* q = Wx_w + row * INSZ + 4 * s;
    v4f t2 = *(const v4f*)q;
    wx2[m][0] = (v2f){t2.x, t2.y};
    wx2[m][1] = (v2f){t2.z, t2.w};
  }
  const float bc = Wx_b[jf] + Wh_b[jf];

  const float* xg = x + (size_t)b * TSTEPS * INSZ;

  // ---- init h0 = 0 ----
  if (tid < 192) hA[tid] = 0.f;

  // ---- stage chunk 0: 512 threads x 16B = 8KB ----
  {
    const AS1 float* gp = (const AS1 float*)(xg + tid * 4);
    AS3 float* d = (AS3 float*)(&xsm[0][(tid >> 6) * 256]);
    __builtin_amdgcn_global_load_lds(gp, d, 16, 0, 0);
  }
  asm volatile("s_waitcnt vmcnt(0) lgkmcnt(0)\ns_barrier" ::: "memory");

  // ---- recurrence ----
  for (int tc = 0; tc < NCHUNK; ++tc) {
    if (tc + 1 < NCHUNK) {
      const AS1 float* gp =
          (const AS1 float*)(xg + (size_t)(tc + 1) * CHUNK * INSZ + tid * 4);
      AS3 float* d = (AS3 float*)(&xsm[(tc + 1) & 1][(tid >> 6) * 256]);
      __builtin_amdgcn_global_load_lds(gp, d, 16, 0, 0);
    }
    const float* xc = xsm[tc & 1];
    v4f xcur = *(const v4f*)&xc[4 * s];  // ts = 0 (buffer just drained)

#pragma unroll
    for (int ts = 0; ts < CHUNK; ++ts) {
      const float* hin = (ts & 1) ? hB : hA;  // parity static (CHUNK even)
      float* hout = (ts & 1) ? hA : hB;

      // h reads at step head (the only exposed LDS latency)
      const float* hp = hin + 12 * s;
      v4f h0 = *(const v4f*)hp;
      v4f h1 = *(const v4f*)(hp + 4);

      // prefetch next step's x (no h dependency; latency hidden a full step)
      v4f xnext;
      if (ts + 1 < CHUNK) xnext = *(const v4f*)&xc[(ts + 1) * INSZ + 4 * s];

      v2f xx0 = (v2f){xcur.x, xcur.y}, xx1 = (v2f){xcur.z, xcur.w};
      v2f hx0 = (v2f){h0.x, h0.y}, hx1 = (v2f){h0.z, h0.w};
      v2f hx2 = (v2f){h1.x, h1.y}, hx3 = (v2f){h1.z, h1.w};

      // ---- x-part: 8 packed ops (executes while h reads are in flight) ----
      v2f ac0, ac1, ac2, ac3;
      asm("v_pk_mul_f32 %0, %4, %12\n\t"
          "v_pk_mul_f32 %1, %6, %12\n\t"
          "v_pk_mul_f32 %2, %8, %12\n\t"
          "v_pk_mul_f32 %3, %10, %12\n\t"
          "v_pk_fma_f32 %0, %5, %13, %0\n\t"
          "v_pk_fma_f32 %1, %7, %13, %1\n\t"
          "v_pk_fma_f32 %2, %9, %13, %2\n\t"
          "v_pk_fma_f32 %3, %11, %13, %3"
          : "=&v"(ac0), "=&v"(ac1), "=&v"(ac2), "=&v"(ac3)
          : "v"(wx2[0][0]), "v"(wx2[0][1]),
            "v"(wx2[1][0]), "v"(wx2[1][1]),
            "v"(wx2[2][0]), "v"(wx2[2][1]),
            "v"(wx2[3][0]), "v"(wx2[3][1]),
            "v"(xx0), "v"(xx1));

      // ---- h-part: 16 packed fma, round-robin over the 4 accumulators ----
      asm("v_pk_fma_f32 %0, %4, %20, %0\n\t"
          "v_pk_fma_f32 %1, %8, %20, %1\n\t"
          "v_pk_fma_f32 %2, %12, %20, %2\n\t"
          "v_pk_fma_f32 %3, %16, %20, %3\n\t"
          "v_pk_fma_f32 %0, %5, %21, %0\n\t"
          "v_pk_fma_f32 %1, %9, %21, %1\n\t"
          "v_pk_fma_f32 %2, %13, %21, %2\n\t"
          "v_pk_fma_f32 %3, %17, %21, %3\n\t"
          "v_pk_fma_f32 %0, %6, %22, %0\n\t"
          "v_pk_fma_f32 %1, %10, %22, %1\n\t"
          "v_pk_fma_f32 %2, %14, %22, %2\n\t"
          "v_pk_fma_f32 %3, %18, %22, %3\n\t"
          "v_pk_fma_f32 %0, %7, %23, %0\n\t"
          "v_pk_fma_f32 %1, %11, %23, %1\n\t"
          "v_pk_fma_f32 %2, %15, %23, %2\n\t"
          "v_pk_fma_f32 %3, %19, %23, %3"
          : "+v"(ac0), "+v"(ac1), "+v"(ac2), "+v"(ac3)
          : "v"(wh2[0][0]), "v"(wh2[0][1]), "v"(wh2[0][2]), "v"(wh2[0][3]),
            "v"(wh2[1][0]), "v"(wh2[1][1]), "v"(wh2[1][2]), "v"(wh2[1][3]),
            "v"(wh2[2][0]), "v"(wh2[2][1]), "v"(wh2[2][2]), "v"(wh2[2][3]),
            "v"(wh2[3][0]), "v"(wh2[3][1]), "v"(wh2[3][2]), "v"(wh2[3][3]),
            "v"(hx0), "v"(hx1), "v"(hx2), "v"(hx3));

      float a0 = ac0.x + ac0.y;
      float a1 = ac1.x + ac1.y;
      float a2 = ac2.x + ac2.y;
      float a3 = ac3.x + ac3.y;

      // DPP butterfly reduce-scatter over the 16-lane k-group
      float b0 = a0 + dppf<DPP_XOR1>(a1);
      float b1 = a2 + dppf<DPP_XOR1>(a3);
      float w  = b0 + dppf<DPP_XOR2>(b1);
      float u  = w + dppf<DPP_XOR15>(w);
      float z  = u + dppf<DPP_XOR8>(u);

      // tanh(z+bc) = 1 - 2/(exp2(2*(z+bc)*log2e)+1)
      z += bc;
      float e = __builtin_amdgcn_exp2f(z * 2.8853900817779268f);
      float hn = fmaf(-2.f, __builtin_amdgcn_rcpf(e + 1.f), 1.f);

      if (s < 4) hout[jp] = hn;  // lanes s=0..3 hold j=4g+s

      if (ts + 1 < CHUNK) xcur = xnext;

      if (ts == CHUNK - 1) {
        // vmcnt drain folded here: next chunk's loads are 31 steps old -> free
        asm volatile("s_waitcnt vmcnt(0) lgkmcnt(0)\ns_barrier" ::: "memory");
      } else {
        asm volatile("s_waitcnt lgkmcnt(0)\ns_barrier" ::: "memory");
      }
    }
  }

  // ---- epilogue: logits + softmax over 64, one wave; final h in hA ----
  if (tid < 64) {
    float acc = fc_b[tid];
    const float* fr = fc_w + tid * HID;
#pragma unroll
    for (int k8 = 0; k8 < 16; ++k8) {
      v4f w0 = *(const v4f*)(fr + 8 * k8);
      v4f w1 = *(const v4f*)(fr + 8 * k8 + 4);
      const float* hh = &hA[12 * k8];
      v4f p0 = *(const v4f*)hh;
      v4f p1 = *(const v4f*)(hh + 4);
      acc = fmaf(w0.x, p0.x, acc);
      acc = fmaf(w0.y, p0.y, acc);
      acc = fmaf(w0.z, p0.z, acc);
      acc = fmaf(w0.w, p0.w, acc);
      acc = fmaf(w1.x, p1.x, acc);
      acc = fmaf(w1.y, p1.y, acc);
      acc = fmaf(w1.z, p1.z, acc);
      acc = fmaf(w1.w, p1.w, acc);
    }
    float m = acc;
#pragma unroll
    for (int off = 32; off >= 1; off >>= 1) m = fmaxf(m, __shfl_xor(m, off, 64));
    float e = __builtin_amdgcn_exp2f((acc - m) * 1.4426950408889634f);
    float ssum = e;
#pragma unroll
    for (int off = 32; off >= 1; off >>= 1) ssum += __shfl_xor(ssum, off, 64);
    out[b * OUTSZ + tid] = e / ssum;
  }
}

extern "C" void kernel_launch(void* const* d_in, const int* in_sizes, int n_in,
                              void* d_out, int out_size, void* d_ws, size_t ws_size,
                              hipStream_t stream) {
  const float* x    = (const float*)d_in[0];
  const float* Wx_w = (const float*)d_in[1];
  const float* Wx_b = (const float*)d_in[2];
  const float* Wh_w = (const float*)d_in[3];
  const float* Wh_b = (const float*)d_in[4];
  const float* fc_w = (const float*)d_in[5];
  const float* fc_b = (const float*)d_in[6];
  float* out = (float*)d_out;

  rnn_masm_kernel<<<BATCH, NTHR, 0, stream>>>(x, Wx_w, Wx_b, Wh_w, Wh_b, fc_w, fc_b, out);
}